// Round 1
// baseline (2659.472 us; speedup 1.0000x reference)
//
#include <hip/hip_runtime.h>

#define TS 500      // n_patch (sequence length)
#define NB 16       // batch
#define NROW 8000   // NB * TS
#define DMODEL 256
#define NHEAD 8
#define HDIM 32
#define FFD 1024

__device__ __forceinline__ float wred_sum(float v) {
    #pragma unroll
    for (int off = 32; off; off >>= 1) v += __shfl_xor(v, off, 64);
    return v;
}
__device__ __forceinline__ float wred_max(float v) {
    #pragma unroll
    for (int off = 32; off; off >>= 1) v = fmaxf(v, __shfl_xor(v, off, 64));
    return v;
}

// LayerNorm of one 256-float LDS row, performed by one wave (lane = 0..63).
__device__ __forceinline__ void row_ln_256(float* rowp, int lane,
                                           const float* __restrict__ g,
                                           const float* __restrict__ bb,
                                           float eps) {
    float v[4];
    float s = 0.f;
    #pragma unroll
    for (int u = 0; u < 4; u++) { v[u] = rowp[lane + u * 64]; s += v[u]; }
    s = wred_sum(s);
    float mu = s * (1.0f / 256.0f);
    float s2 = 0.f;
    #pragma unroll
    for (int u = 0; u < 4; u++) { float d = v[u] - mu; s2 += d * d; }
    s2 = wred_sum(s2);
    float rs = rsqrtf(s2 * (1.0f / 256.0f) + eps);
    #pragma unroll
    for (int u = 0; u < 4; u++) {
        int k = lane + u * 64;
        rowp[k] = (v[u] - mu) * rs * g[k] + bb[k];
    }
}

// ---------------------------------------------------------------------------
// Stage 1: patchify (4x128 -> 512) + LN1 + proj (512->256) + LN2
// 8 rows per block, 256 threads.
// ---------------------------------------------------------------------------
__global__ __launch_bounds__(256) void k_patch(
    const float* __restrict__ x, const float* __restrict__ g1, const float* __restrict__ b1,
    const float* __restrict__ pw, const float* __restrict__ pb,
    const float* __restrict__ g2, const float* __restrict__ b2,
    float* __restrict__ hout)
{
    __shared__ float xs[8][512];
    __shared__ float red[4][8];
    int t = threadIdx.x;
    int lane = t & 63, wave = t >> 6;
    int row0 = blockIdx.x * 8;

    for (int idx = t; idx < 8 * 512; idx += 256) {
        int r = idx >> 9, k = idx & 511;
        int row = row0 + r;
        int b = row / TS, p = row - b * TS;
        xs[r][k] = x[((p * 4 + (k >> 7)) * NB + b) * 128 + (k & 127)];
    }
    __syncthreads();

    // LN1 over 512 features, wave w handles rows w and w+4
    #pragma unroll
    for (int rr = 0; rr < 2; rr++) {
        int r = wave + rr * 4;
        float v[8];
        float s = 0.f;
        #pragma unroll
        for (int u = 0; u < 8; u++) { v[u] = xs[r][lane + u * 64]; s += v[u]; }
        s = wred_sum(s);
        float mu = s * (1.0f / 512.0f);
        float s2 = 0.f;
        #pragma unroll
        for (int u = 0; u < 8; u++) { float d = v[u] - mu; s2 += d * d; }
        s2 = wred_sum(s2);
        float rs = rsqrtf(s2 * (1.0f / 512.0f) + 1e-6f);
        #pragma unroll
        for (int u = 0; u < 8; u++) {
            int k = lane + u * 64;
            xs[r][k] = (v[u] - mu) * rs * g1[k] + b1[k];
        }
    }
    __syncthreads();

    // proj: thread t computes column t for all 8 rows
    float acc[8] = {0.f, 0.f, 0.f, 0.f, 0.f, 0.f, 0.f, 0.f};
    for (int k = 0; k < 512; k++) {
        float w = pw[k * 256 + t];
        #pragma unroll
        for (int r = 0; r < 8; r++) acc[r] += xs[r][k] * w;
    }
    float pbv = pb[t];
    #pragma unroll
    for (int r = 0; r < 8; r++) acc[r] += pbv;

    // LN2 over 256 (value distributed one-per-thread), two-pass
    float mu[8], rs[8];
    #pragma unroll
    for (int r = 0; r < 8; r++) {
        float s = wred_sum(acc[r]);
        if (lane == 0) red[wave][r] = s;
    }
    __syncthreads();
    #pragma unroll
    for (int r = 0; r < 8; r++)
        mu[r] = (red[0][r] + red[1][r] + red[2][r] + red[3][r]) * (1.0f / 256.0f);
    __syncthreads();
    #pragma unroll
    for (int r = 0; r < 8; r++) {
        float d = acc[r] - mu[r];
        float s2 = wred_sum(d * d);
        if (lane == 0) red[wave][r] = s2;
    }
    __syncthreads();
    #pragma unroll
    for (int r = 0; r < 8; r++)
        rs[r] = rsqrtf((red[0][r] + red[1][r] + red[2][r] + red[3][r]) * (1.0f / 256.0f) + 1e-6f);

    float gv = g2[t], bv = b2[t];
    #pragma unroll
    for (int r = 0; r < 8; r++)
        hout[(row0 + r) * 256 + t] = (acc[r] - mu[r]) * rs[r] * gv + bv;
}

// ---------------------------------------------------------------------------
// Per-layer: LN + QKV GEMM (256 -> 768). 8 rows per block.
// ---------------------------------------------------------------------------
__global__ __launch_bounds__(256) void k_ln_qkv(
    const float* __restrict__ h, const float* __restrict__ g, const float* __restrict__ bb,
    const float* __restrict__ qw, const float* __restrict__ qb,
    float* __restrict__ qkv)
{
    __shared__ float xs[8][256];
    int t = threadIdx.x, lane = t & 63, wave = t >> 6;
    int row0 = blockIdx.x * 8;

    for (int idx = t; idx < 8 * 256; idx += 256)
        xs[idx >> 8][idx & 255] = h[row0 * 256 + idx];
    __syncthreads();
    #pragma unroll
    for (int rr = 0; rr < 2; rr++) row_ln_256(&xs[wave + rr * 4][0], lane, g, bb, 1e-5f);
    __syncthreads();

    float a0[8] = {}, a1[8] = {}, a2[8] = {};
    for (int k = 0; k < 256; k++) {
        float w0 = qw[k * 768 + t];
        float w1 = qw[k * 768 + 256 + t];
        float w2 = qw[k * 768 + 512 + t];
        #pragma unroll
        for (int r = 0; r < 8; r++) {
            float xv = xs[r][k];
            a0[r] += xv * w0; a1[r] += xv * w1; a2[r] += xv * w2;
        }
    }
    float qb0 = qb[t], qb1 = qb[256 + t], qb2 = qb[512 + t];
    #pragma unroll
    for (int r = 0; r < 8; r++) {
        int row = row0 + r;
        qkv[row * 768 + t]       = a0[r] + qb0;
        qkv[row * 768 + 256 + t] = a1[r] + qb1;
        qkv[row * 768 + 512 + t] = a2[r] + qb2;
    }
}

// ---------------------------------------------------------------------------
// Attention: one block (256 threads) per (query row i, b*NH+h).
// Causal: only j <= i computed. scores + rel_bias, softmax, PV.
// ---------------------------------------------------------------------------
__global__ __launch_bounds__(256) void k_attn(
    const float* __restrict__ qkv, const float* __restrict__ rel_bias,
    float* __restrict__ o)
{
    int i = blockIdx.x;        // 0..499
    int bh = blockIdx.y;       // 0..127
    int b = bh >> 3, hh = bh & 7;
    int t = threadIdx.x, lane = t & 63, wave = t >> 6;

    __shared__ float qv[32];
    __shared__ float sc[512];
    __shared__ float red[4];
    __shared__ float osum[8][32];

    const float* qrow = qkv + (b * TS + i) * 768 + hh * 32;
    if (t < 32) qv[t] = qrow[t];
    __syncthreads();

    const float scale = 0.17677669529663687f;  // 1/sqrt(32)
    float lmax = -1e30f;
    for (int j = t; j <= i; j += 256) {
        const float* krow = qkv + (b * TS + j) * 768 + 256 + hh * 32;
        float d = 0.f;
        #pragma unroll
        for (int u = 0; u < 32; u++) d += qv[u] * krow[u];
        int rel = j - i; if (rel < -64) rel = -64;
        float sv = d * scale + rel_bias[hh * 129 + rel + 64];
        sc[j] = sv;
        lmax = fmaxf(lmax, sv);
    }
    lmax = wred_max(lmax);
    if (lane == 0) red[wave] = lmax;
    __syncthreads();
    float bmax = fmaxf(fmaxf(red[0], red[1]), fmaxf(red[2], red[3]));
    __syncthreads();

    float lsum = 0.f;
    for (int j = t; j <= i; j += 256) {
        float e = __expf(sc[j] - bmax);
        sc[j] = e;
        lsum += e;
    }
    lsum = wred_sum(lsum);
    __syncthreads();
    if (lane == 0) red[wave] = lsum;
    __syncthreads();
    float inv = 1.0f / (red[0] + red[1] + red[2] + red[3]);

    int d = t & 31, slice = t >> 5;
    float acc = 0.f;
    for (int j = slice; j <= i; j += 8)
        acc += sc[j] * qkv[(b * TS + j) * 768 + 512 + hh * 32 + d];
    osum[slice][d] = acc;
    __syncthreads();
    if (slice == 0) {
        float s = 0.f;
        #pragma unroll
        for (int u = 0; u < 8; u++) s += osum[u][d];
        o[(b * TS + i) * 256 + hh * 32 + d] = s * inv;
    }
}

// ---------------------------------------------------------------------------
// Out-projection + residual. 8 rows per block.
// ---------------------------------------------------------------------------
__global__ __launch_bounds__(256) void k_out_res(
    const float* __restrict__ o, const float* __restrict__ ow, const float* __restrict__ ob,
    float* __restrict__ h)
{
    __shared__ float xs[8][256];
    int t = threadIdx.x;
    int row0 = blockIdx.x * 8;
    for (int idx = t; idx < 2048; idx += 256)
        xs[idx >> 8][idx & 255] = o[row0 * 256 + idx];
    __syncthreads();

    float acc[8] = {};
    for (int k = 0; k < 256; k++) {
        float w = ow[k * 256 + t];
        #pragma unroll
        for (int r = 0; r < 8; r++) acc[r] += xs[r][k] * w;
    }
    float obv = ob[t];
    #pragma unroll
    for (int r = 0; r < 8; r++) {
        int idx = (row0 + r) * 256 + t;
        h[idx] += acc[r] + obv;
    }
}

// ---------------------------------------------------------------------------
// FF block: LN + ff1 (256->1024) + exact GELU + ff2 (1024->256) + residual.
// f1 staged in LDS. 8 rows per block.
// ---------------------------------------------------------------------------
__global__ __launch_bounds__(256) void k_ff(
    float* __restrict__ h, const float* __restrict__ g, const float* __restrict__ bb,
    const float* __restrict__ w1, const float* __restrict__ b1,
    const float* __restrict__ w2, const float* __restrict__ b2)
{
    __shared__ float xs[8][256];
    __shared__ float f1[8][1024];
    int t = threadIdx.x, lane = t & 63, wave = t >> 6;
    int row0 = blockIdx.x * 8;

    for (int idx = t; idx < 2048; idx += 256)
        xs[idx >> 8][idx & 255] = h[row0 * 256 + idx];
    __syncthreads();
    #pragma unroll
    for (int rr = 0; rr < 2; rr++) row_ln_256(&xs[wave + rr * 4][0], lane, g, bb, 1e-5f);
    __syncthreads();

    float acc[4][8] = {};
    for (int k = 0; k < 256; k++) {
        float w[4];
        #pragma unroll
        for (int c = 0; c < 4; c++) w[c] = w1[k * 1024 + c * 256 + t];
        #pragma unroll
        for (int r = 0; r < 8; r++) {
            float xv = xs[r][k];
            #pragma unroll
            for (int c = 0; c < 4; c++) acc[c][r] += xv * w[c];
        }
    }
    #pragma unroll
    for (int c = 0; c < 4; c++) {
        float bv = b1[c * 256 + t];
        #pragma unroll
        for (int r = 0; r < 8; r++) {
            float v = acc[c][r] + bv;
            f1[r][c * 256 + t] = 0.5f * v * (1.0f + erff(v * 0.70710678118654752f));
        }
    }
    __syncthreads();

    float a2[8] = {};
    for (int k = 0; k < 1024; k++) {
        float w = w2[k * 256 + t];
        #pragma unroll
        for (int r = 0; r < 8; r++) a2[r] += f1[r][k] * w;
    }
    float bv2 = b2[t];
    #pragma unroll
    for (int r = 0; r < 8; r++) {
        int idx = (row0 + r) * 256 + t;
        h[idx] = h[idx] + a2[r] + bv2;
    }
}

// ---------------------------------------------------------------------------
// Final LN + output projection (256->128), swapaxes write (p, b, f).
// ---------------------------------------------------------------------------
__global__ __launch_bounds__(256) void k_final(
    const float* __restrict__ h, const float* __restrict__ g, const float* __restrict__ bb,
    const float* __restrict__ opw, const float* __restrict__ opb,
    float* __restrict__ out)
{
    __shared__ float xs[8][256];
    int t = threadIdx.x, lane = t & 63, wave = t >> 6;
    int row0 = blockIdx.x * 8;
    for (int idx = t; idx < 2048; idx += 256)
        xs[idx >> 8][idx & 255] = h[row0 * 256 + idx];
    __syncthreads();
    #pragma unroll
    for (int rr = 0; rr < 2; rr++) row_ln_256(&xs[wave + rr * 4][0], lane, g, bb, 1e-5f);
    __syncthreads();

    int col = t & 127, rg = t >> 7;  // rg in {0,1}: rows rg*4..rg*4+3
    float acc[4] = {};
    for (int k = 0; k < 256; k++) {
        float w = opw[k * 128 + col];
        #pragma unroll
        for (int u = 0; u < 4; u++) acc[u] += xs[rg * 4 + u][k] * w;
    }
    float obv = opb[col];
    #pragma unroll
    for (int u = 0; u < 4; u++) {
        int row = row0 + rg * 4 + u;
        int b = row / TS, p = row - b * TS;
        out[(p * NB + b) * 128 + col] = acc[u] + obv;
    }
}

extern "C" void kernel_launch(void* const* d_in, const int* in_sizes, int n_in,
                              void* d_out, int out_size, void* d_ws, size_t ws_size,
                              hipStream_t stream)
{
    const float* x        = (const float*)d_in[0];
    const float* ln1_g    = (const float*)d_in[1];
    const float* ln1_b    = (const float*)d_in[2];
    const float* proj_w   = (const float*)d_in[3];
    const float* proj_b   = (const float*)d_in[4];
    const float* ln2_g    = (const float*)d_in[5];
    const float* ln2_b    = (const float*)d_in[6];
    const float* rel_bias = (const float*)d_in[7];
    const float* ln_attn_g= (const float*)d_in[8];
    const float* ln_attn_b= (const float*)d_in[9];
    const float* qkv_w    = (const float*)d_in[10];
    const float* qkv_b    = (const float*)d_in[11];
    const float* out_w    = (const float*)d_in[12];
    const float* out_b    = (const float*)d_in[13];
    const float* ln_ff_g  = (const float*)d_in[14];
    const float* ln_ff_b  = (const float*)d_in[15];
    const float* ff1_w    = (const float*)d_in[16];
    const float* ff1_b    = (const float*)d_in[17];
    const float* ff2_w    = (const float*)d_in[18];
    const float* ff2_b    = (const float*)d_in[19];
    const float* fln_g    = (const float*)d_in[20];
    const float* fln_b    = (const float*)d_in[21];
    const float* op_w     = (const float*)d_in[22];
    const float* op_b     = (const float*)d_in[23];
    float* out = (float*)d_out;

    float* h   = (float*)d_ws;            // NROW*256
    float* qkv = h + NROW * DMODEL;       // NROW*768
    float* o   = qkv + NROW * 768;        // NROW*256

    k_patch<<<NROW / 8, 256, 0, stream>>>(x, ln1_g, ln1_b, proj_w, proj_b, ln2_g, ln2_b, h);
    for (int l = 0; l < 4; l++) {
        k_ln_qkv<<<NROW / 8, 256, 0, stream>>>(h, ln_attn_g + l * 256, ln_attn_b + l * 256,
                                               qkv_w + l * 256 * 768, qkv_b + l * 768, qkv);
        dim3 ag(TS, NB * NHEAD);
        k_attn<<<ag, 256, 0, stream>>>(qkv, rel_bias, o);
        k_out_res<<<NROW / 8, 256, 0, stream>>>(o, out_w + l * 256 * 256, out_b + l * 256, h);
        k_ff<<<NROW / 8, 256, 0, stream>>>(h, ln_ff_g + l * 256, ln_ff_b + l * 256,
                                           ff1_w + l * 256 * 1024, ff1_b + l * 1024,
                                           ff2_w + l * 1024 * 256, ff2_b + l * 256);
    }
    k_final<<<NROW / 8, 256, 0, stream>>>(h, fln_g, fln_b, op_w, op_b, out);
}